// Round 7
// baseline (280.880 us; speedup 1.0000x reference)
//
#include <hip/hip_runtime.h>
#include <hip/hip_bf16.h>
#include <math.h>

#define B_ 1024
#define S_ 200
#define D_ 128
#define H_ 128
#define N_ 64

typedef __attribute__((ext_vector_type(8))) short short8;
typedef __attribute__((ext_vector_type(8))) __bf16 bf16x8;
typedef __attribute__((ext_vector_type(4))) float floatx4;

static __device__ __forceinline__ float bf2f(unsigned short u) {
    union { unsigned int i; float f; } v; v.i = ((unsigned int)u) << 16; return v.f;
}
static __device__ __forceinline__ unsigned short f2bf(float f) {
    union { float f; unsigned int u; } v; v.f = f;
    unsigned int u = v.u;
    return (unsigned short)((u + 0x7FFFu + ((u >> 16) & 1u)) >> 16);   // RNE
}
static __device__ __forceinline__ float ld1(const void* p, int isbf, size_t i) {
    return isbf ? bf2f(((const unsigned short*)p)[i]) : ((const float*)p)[i];
}
static __device__ __forceinline__ float fast_tanh(float x) {
    float t = __expf(2.0f * x);
    return 1.0f - 2.0f * __builtin_amdgcn_rcpf(t + 1.0f);   // err ~2e-5
}

// ---------------- K-1: dtype detection ----------------
__global__ __launch_bounds__(64) void detect_kernel(
    const void* a0, const void* a1, const void* a2, const void* a3,
    const void* a4, const void* a5, const void* a6, const void* a7,
    int* flags)
{
    int bid = blockIdx.x, t = threadIdx.x;
    if (bid == 3) {
        const unsigned char* mb = (const unsigned char*)a3;
        int f = 0;
        for (int i = t; i < 4096; i += 64)
            if ((i & 3) && mb[i]) f = 1;
        for (int off = 32; off; off >>= 1) f |= __shfl_xor(f, off, 64);
        if (t == 0) flags[3] = f;          // 1 => uint8 mask, 0 => int32 mask
        return;
    }
    const void* ptrs[8] = {a0, a1, a2, a3, a4, a5, a6, a7};
    const int counts[8] = {B_*S_*D_, S_*D_, B_*D_, 0, B_*N_*D_, D_*H_, D_*H_, H_};
    const unsigned int* w = (const unsigned int*)ptrs[bid];
    int words = counts[bid] / 2; if (words > 1024) words = 1024;
    int pass = 0, tot = 0;
    for (int i = t; i < words; i += 64) {
        unsigned int e = (w[i] >> 7) & 0xFF;
        tot++;
        if (e == 0 || (e >= 96 && e <= 140)) pass++;
    }
    for (int off = 32; off; off >>= 1) {
        pass += __shfl_xor(pass, off, 64);
        tot  += __shfl_xor(tot,  off, 64);
    }
    if (t == 0) flags[bid] = (pass * 4 >= tot * 3) ? 1 : 0;
}

// ---------------- lengths[b] = popcount(valid_mask[b,:]) (prefix mask) ----------------
__global__ __launch_bounds__(256) void lengths_kernel(
    const void* __restrict__ maskv, const int* __restrict__ flags,
    int* __restrict__ lengths)
{
    int wv = threadIdx.x >> 6, lane = threadIdx.x & 63;
    int fMk = flags[3];
    int base = blockIdx.x * 64 + wv * 16;      // 16 b per wave
    for (int bb = 0; bb < 16; ++bb) {
        int b = base + bb;
        int nz = 0;
        if (fMk) {
            const unsigned char* mb = (const unsigned char*)maskv + (size_t)b * S_;
            for (int i = lane; i < S_; i += 64) nz += (mb[i] != 0);
        } else {
            const int* mi = (const int*)maskv + (size_t)b * S_;
            for (int i = lane; i < S_; i += 64) nz += (mi[i] != 0);
        }
        for (int off = 32; off; off >>= 1) nz += __shfl_xor(nz, off, 64);
        if (lane == 0) lengths[b] = nz;
    }
}

// ---------------- prep: block 0 -> WeTf (fragment-swizzled); blocks 1..200 -> pb rows ----
// WeTf layout: frag = nt*4+kks; WeTf[(frag*64+lane)*8+j] = We[kks*32+(lane>>4)*8+j][nt*16+(lane&15)]
__global__ __launch_bounds__(128) void prep_kernel(
    const void* __restrict__ We, const void* __restrict__ pos,
    const void* __restrict__ Wp, const int* __restrict__ flags,
    unsigned short* __restrict__ WeTf, float* __restrict__ pb)
{
    int blk = blockIdx.x, t = threadIdx.x;
    __shared__ unsigned short T[128][136];
    __shared__ float prow[D_];
    if (blk == 0) {
        int fWe = flags[6];
        for (int c = t; c < 2048; c += 128) {
            int d = c >> 4, h8 = (c & 15) * 8;
            short8 v;
            if (fWe) {
                v = *(const short8*)((const unsigned short*)We + d * H_ + h8);
            } else {
                const float* p = (const float*)We + d * H_ + h8;
                float4 a = ((const float4*)p)[0], b = ((const float4*)p)[1];
                v[0] = (short)f2bf(a.x); v[1] = (short)f2bf(a.y);
                v[2] = (short)f2bf(a.z); v[3] = (short)f2bf(a.w);
                v[4] = (short)f2bf(b.x); v[5] = (short)f2bf(b.y);
                v[6] = (short)f2bf(b.z); v[7] = (short)f2bf(b.w);
            }
            *(short8*)(&T[d][h8]) = v;
        }
        __syncthreads();
        for (int i = t; i < 2048; i += 128) {
            int frag = i >> 6, ln = i & 63;
            int nt = frag >> 2, kks = frag & 3;
            int h = nt * 16 + (ln & 15);
            int dbase = kks * 32 + (ln >> 4) * 8;
            short8 v;
#pragma unroll
            for (int j = 0; j < 8; ++j) v[j] = (short)T[dbase + j][h];
            *(short8*)(WeTf + (size_t)i * 8) = v;
        }
    } else {
        int s = blk - 1, h = t;
        prow[h] = ld1(pos, flags[1], (size_t)s * D_ + h);
        __syncthreads();
        float acc = 0.f;
        if (flags[5]) {
            const unsigned short* W = (const unsigned short*)Wp;
            for (int d = 0; d < D_; ++d) acc = fmaf(prow[d], bf2f(W[d * H_ + h]), acc);
        } else {
            const float* W = (const float*)Wp;
            for (int d = 0; d < D_; ++d) acc = fmaf(prow[d], W[d * H_ + h], acc);
        }
        pb[s * H_ + h] = acc;
    }
}

// ---------------- K1: scores GEMM — skips m-tiles with no valid row ----------------
// Block = 256 thr (4 waves), M = 128 rows/block (2 m-tiles/wave), grid = 1600.
__global__ __launch_bounds__(256) void scores_kernel(
    const void* __restrict__ Xs, const unsigned short* __restrict__ WeTf,
    const void* __restrict__ zv, const float* __restrict__ pb,
    const int* __restrict__ flags, const int* __restrict__ lengths,
    float* __restrict__ scores)
{
    __shared__ unsigned short Bsh[16384];   // 32 KB, frag-contiguous (same layout as WeTf)
    int t = threadIdx.x;
    int lane = t & 63, w = t >> 6;
    int quad = lane >> 4, mrow = lane & 15;
    int fXs = flags[0], fz = flags[7];
    int row0 = blockIdx.x * 128 + w * 32;

    // one-time B stage: 8 coalesced 16B copies per thread
    for (int i = t; i < 2048; i += 256)
        *(short8*)(Bsh + i * 8) = *(const short8*)(WeTf + (size_t)i * 8);

    float zl[8];
#pragma unroll
    for (int nt = 0; nt < 8; ++nt) zl[nt] = ld1(zv, fz, nt * 16 + mrow);
    __syncthreads();

#pragma unroll
    for (int mt = 0; mt < 2; ++mt) {
        int r = row0 + mt * 16 + mrow;          // this lane's A row
        int bidx = r / S_, s_ = r - bidx * S_;
        bool valid = s_ < lengths[bidx];
        if (!__any(valid)) continue;             // wave-uniform tile skip

        floatx4 acc[8];
#pragma unroll
        for (int nt = 0; nt < 8; ++nt) {
            acc[nt][0] = 0.f; acc[nt][1] = 0.f; acc[nt][2] = 0.f; acc[nt][3] = 0.f;
        }
#pragma unroll
        for (int kks = 0; kks < 4; ++kks) {
            bf16x8 af;
            size_t roff = (size_t)r * D_ + kks * 32 + quad * 8;
            if (fXs) {
                short8 v = *(const short8*)((const unsigned short*)Xs + roff);
                af = __builtin_bit_cast(bf16x8, v);
            } else {
                const float* p = (const float*)Xs + roff;
                float4 a = ((const float4*)p)[0], b = ((const float4*)p)[1];
                short8 v;
                v[0] = (short)f2bf(a.x); v[1] = (short)f2bf(a.y);
                v[2] = (short)f2bf(a.z); v[3] = (short)f2bf(a.w);
                v[4] = (short)f2bf(b.x); v[5] = (short)f2bf(b.y);
                v[6] = (short)f2bf(b.z); v[7] = (short)f2bf(b.w);
                af = __builtin_bit_cast(bf16x8, v);
            }
#pragma unroll
            for (int nt = 0; nt < 8; ++nt) {
                short8 bv = *(const short8*)(Bsh + (((nt << 2) + kks) * 64 + lane) * 8);
                bf16x8 bf = __builtin_bit_cast(bf16x8, bv);
                acc[nt] = __builtin_amdgcn_mfma_f32_16x16x32_bf16(af, bf, acc[nt], 0, 0, 0);
            }
        }
        // epilogue: C layout col=mrow, row=quad*4+reg
#pragma unroll
        for (int reg = 0; reg < 4; ++reg) {
            int grow = row0 + mt * 16 + quad * 4 + reg;
            int s = grow % S_;
            const float* pbrow = pb + (size_t)s * H_;
            float rs = 0.f;
#pragma unroll
            for (int nt = 0; nt < 8; ++nt)
                rs = fmaf(fast_tanh(acc[nt][reg] + pbrow[nt * 16 + mrow]), zl[nt], rs);
#pragma unroll
            for (int off = 1; off < 16; off <<= 1)
                rs += __shfl_xor(rs, off, 64);
            if (mrow == 0) scores[grow] = rs;
        }
    }
}

// ---------------- K2: per-b softmax, weighted sum, inner, pos/neg losses ----------------
__global__ __launch_bounds__(256) void attnout_kernel(
    const void* __restrict__ Xs, const void* __restrict__ Xitem,
    const void* __restrict__ origin, const float* __restrict__ scores,
    const int* __restrict__ flags, const int* __restrict__ lengths,
    float* __restrict__ pos_loss, float* __restrict__ neg_sum,
    float* __restrict__ out)
{
    int b = blockIdx.x, t = threadIdx.x;
    int wv = t >> 6, lane = t & 63;
    int fXs = flags[0], fXi = flags[2], fOr = flags[4];
    __shared__ float attn[256];
    __shared__ float att_out[D_];
    __shared__ float lastv[D_];
    __shared__ float outv[D_];
    __shared__ float partial[8][D_];
    __shared__ float p_oo[4][64];
    __shared__ float p_ov[4][64];
    __shared__ float red[16];
    __shared__ float sc1s, sc2s, vvs;

    // --- preload this thread's origin slice into registers (latency hidden) ---
    int nn = t >> 2, part = t & 3;       // thread -> (n, quarter-of-D)
    float o_f[32];
    if (fOr) {
        const unsigned short* p = (const unsigned short*)origin + ((size_t)b * N_ + nn) * D_ + part * 32;
#pragma unroll
        for (int j = 0; j < 4; ++j) {
            uint4 u = *(const uint4*)(p + j * 8);
            o_f[j*8+0] = bf2f((unsigned short)(u.x & 0xffff));
            o_f[j*8+1] = bf2f((unsigned short)(u.x >> 16));
            o_f[j*8+2] = bf2f((unsigned short)(u.y & 0xffff));
            o_f[j*8+3] = bf2f((unsigned short)(u.y >> 16));
            o_f[j*8+4] = bf2f((unsigned short)(u.z & 0xffff));
            o_f[j*8+5] = bf2f((unsigned short)(u.z >> 16));
            o_f[j*8+6] = bf2f((unsigned short)(u.w & 0xffff));
            o_f[j*8+7] = bf2f((unsigned short)(u.w >> 16));
        }
    } else {
        const float* p = (const float*)origin + ((size_t)b * N_ + nn) * D_ + part * 32;
#pragma unroll
        for (int j = 0; j < 8; ++j) {
            float4 v = *(const float4*)(p + j * 4);
            o_f[j*4+0] = v.x; o_f[j*4+1] = v.y; o_f[j*4+2] = v.z; o_f[j*4+3] = v.w;
        }
    }

    int length = lengths[b];      // >= 1
    int last = length - 1;

    // --- softmax over valid prefix ---
    float sc = (t < length) ? scores[(size_t)b * S_ + t] : -INFINITY;
    float m = sc;
    for (int off = 32; off; off >>= 1) m = fmaxf(m, __shfl_xor(m, off, 64));
    if (lane == 0) red[wv] = m;
    __syncthreads();
    if (t == 0) sc1s = fmaxf(fmaxf(red[0], red[1]), fmaxf(red[2], red[3]));
    __syncthreads();
    float e = (t < length) ? expf(sc - sc1s) : 0.f;
    float r = e;
    for (int off = 32; off; off >>= 1) r += __shfl_xor(r, off, 64);
    __syncthreads();
    if (lane == 0) red[wv] = r;
    __syncthreads();
    if (t == 0) sc2s = red[0] + red[1] + red[2] + red[3];
    __syncthreads();
    attn[t] = e / sc2s;       // 0 beyond length (incl. 200..255)
    __syncthreads();

    // --- attention_output[d] = sum_{s<length} attn[s] * X[b,s,d] (uniform bound) ---
    {
        int sp = t >> 5;               // s offset 0..7
        int d4 = (t & 31) * 4;         // 4 contiguous d
        float a0 = 0, a1 = 0, a2 = 0, a3 = 0;
        if (fXs) {
#pragma unroll 5
            for (int s = sp; s < length; s += 8) {
                float ww = attn[s];
                uint2 u = *(const uint2*)((const unsigned short*)Xs + ((size_t)b * S_ + s) * D_ + d4);
                a0 = fmaf(ww, bf2f((unsigned short)(u.x & 0xffff)), a0);
                a1 = fmaf(ww, bf2f((unsigned short)(u.x >> 16)), a1);
                a2 = fmaf(ww, bf2f((unsigned short)(u.y & 0xffff)), a2);
                a3 = fmaf(ww, bf2f((unsigned short)(u.y >> 16)), a3);
            }
        } else {
#pragma unroll 5
            for (int s = sp; s < length; s += 8) {
                float ww = attn[s];
                float4 u = *(const float4*)((const float*)Xs + ((size_t)b * S_ + s) * D_ + d4);
                a0 = fmaf(ww, u.x, a0);
                a1 = fmaf(ww, u.y, a1);
                a2 = fmaf(ww, u.z, a2);
                a3 = fmaf(ww, u.w, a3);
            }
        }
        partial[sp][d4] = a0; partial[sp][d4 + 1] = a1;
        partial[sp][d4 + 2] = a2; partial[sp][d4 + 3] = a3;
    }
    __syncthreads();
    if (t < D_) {
        float v = 0.f;
#pragma unroll
        for (int p = 0; p < 8; ++p) v += partial[p][t];
        att_out[t] = v;
        float lv = attn[last] * ld1(Xs, fXs, ((size_t)b * S_ + last) * D_ + t);
        lastv[t] = lv;
        outv[t] = v - lv;       // out_vec = attention_output - last_vec
    }
    __syncthreads();

    // --- inner = dot(att_out, X_item[b]); write concated row (f32) ---
    {
        float pi = (t < D_) ? att_out[t] * ld1(Xitem, fXi, (size_t)b * D_ + t) : 0.f;
        for (int off = 32; off; off >>= 1) pi += __shfl_xor(pi, off, 64);
        if (lane == 0) red[wv] = pi;
        __syncthreads();
        if (t < D_) out[(size_t)b * (D_ + 1) + t] = att_out[t];
        if (t == 0)
            out[(size_t)b * (D_ + 1) + D_] = red[0] + red[1] + red[2] + red[3];
        __syncthreads();
    }

    // --- pos loss: cos(last_vec, out_vec) ---
    {
        float l_ = (t < D_) ? lastv[t] : 0.f;
        float o_ = (t < D_) ? outv[t] : 0.f;
        float r0 = l_ * l_, r1 = l_ * o_, r2 = o_ * o_;
        for (int off = 32; off; off >>= 1) {
            r0 += __shfl_xor(r0, off, 64);
            r1 += __shfl_xor(r1, off, 64);
            r2 += __shfl_xor(r2, off, 64);
        }
        if (lane == 0) { red[wv] = r0; red[4 + wv] = r1; red[8 + wv] = r2; }
        __syncthreads();
        if (t == 0) {
            float ll = red[0] + red[1] + red[2] + red[3];
            float lo = red[4] + red[5] + red[6] + red[7];
            float oo = red[8] + red[9] + red[10] + red[11];
            float cosv = lo / (sqrtf(fmaxf(ll, 1e-12f)) * sqrtf(fmaxf(oo, 1e-12f)));
            float pl = 0.5f * (1.f - cosv);
            pos_loss[b] = log1pf(expf(-pl));
            vvs = oo;
        }
        __syncthreads();
    }

    // --- neg losses: thread (nn,part) computes quarter-dot; LDS reduce ---
    {
        float o_oo = 0.f, o_ov = 0.f;
#pragma unroll
        for (int jj = 0; jj < 32; ++jj) {
            int j = (jj + part * 8) & 31;           // bank-rotated outv read
            float wv_ = outv[part * 32 + j];
            o_oo = fmaf(o_f[j], o_f[j], o_oo);
            o_ov = fmaf(o_f[j], wv_, o_ov);
        }
        p_oo[part][nn] = o_oo;
        p_ov[part][nn] = o_ov;
        __syncthreads();
        if (t < 64) {
            float oo = p_oo[0][t] + p_oo[1][t] + p_oo[2][t] + p_oo[3][t];
            float ov = p_ov[0][t] + p_ov[1][t] + p_ov[2][t] + p_ov[3][t];
            float cosn = ov / (sqrtf(fmaxf(oo, 1e-12f)) * sqrtf(fmaxf(vvs, 1e-12f)));
            float nl = 0.5f * (1.f - cosn);
            float nloss = log1pf(expf(nl));
            for (int off = 32; off; off >>= 1) nloss += __shfl_xor(nloss, off, 64);
            if (t == 0) neg_sum[b] = nloss;
        }
    }
}

// ---------------- K3: aux[b] = sum_b'(pos_loss) + neg_sum[b] (f32) ----------------
__global__ __launch_bounds__(1024) void final_kernel(
    const float* __restrict__ pos_loss,
    const float* __restrict__ neg_sum,
    float* __restrict__ out)
{
    __shared__ float red[16];
    int t = threadIdx.x;
    float v = pos_loss[t];
    for (int off = 32; off; off >>= 1) v += __shfl_xor(v, off, 64);
    if ((t & 63) == 0) red[t >> 6] = v;
    __syncthreads();
    if (t == 0) {
        float s = 0.f;
#pragma unroll
        for (int i = 0; i < 16; ++i) s += red[i];
        red[0] = s;
    }
    __syncthreads();
    out[(size_t)B_ * (D_ + 1) + t] = red[0] + neg_sum[t];
}

extern "C" void kernel_launch(void* const* d_in, const int* in_sizes, int n_in,
                              void* d_out, int out_size, void* d_ws, size_t ws_size,
                              hipStream_t stream) {
    const void* Xs     = d_in[0]; // X_series [B,S,D]
    const void* pos    = d_in[1]; // pos_series [S,D]
    const void* Xitem  = d_in[2]; // X_item [B,D]
    const void* mask   = d_in[3]; // valid_mask [B,S]
    const void* origin = d_in[4]; // origin [B,N,D]
    const void* Wp     = d_in[5]; // [D,H]
    const void* We     = d_in[6]; // [D,H]
    const void* zv     = d_in[7]; // [H]

    int*   flags    = (int*)d_ws;                                  // 128 B
    unsigned short* WeTf = (unsigned short*)((char*)d_ws + 128);   // 32 KB swizzled
    float* pb       = (float*)((char*)d_ws + 128 + 32768);         // 25600 f32
    float* scores   = pb + 25600;                                  // 204800 f32
    float* pos_loss = scores + 204800;                             // 1024 f32
    float* neg_sum  = pos_loss + B_;                               // 1024 f32
    int*   lengths  = (int*)(neg_sum + B_);                        // 1024 i32
    float* out = (float*)d_out;                                    // f32 output

    detect_kernel<<<8, 64, 0, stream>>>(Xs, pos, Xitem, mask, origin, Wp, We, zv, flags);
    lengths_kernel<<<16, 256, 0, stream>>>(mask, flags, lengths);
    prep_kernel<<<201, 128, 0, stream>>>(We, pos, Wp, flags, WeTf, pb);
    scores_kernel<<<(B_ * S_) / 128, 256, 0, stream>>>(Xs, WeTf, zv, pb, flags, lengths, scores);
    attnout_kernel<<<B_, 256, 0, stream>>>(Xs, Xitem, origin, scores, flags, lengths,
                                           pos_loss, neg_sum, out);
    final_kernel<<<1, 1024, 0, stream>>>(pos_loss, neg_sum, out);
}

// Round 8
// 274.027 us; speedup vs baseline: 1.0250x; 1.0250x over previous
//
#include <hip/hip_runtime.h>
#include <hip/hip_bf16.h>
#include <math.h>

#define B_ 1024
#define S_ 200
#define D_ 128
#define H_ 128
#define N_ 64

typedef __attribute__((ext_vector_type(8))) short short8;
typedef __attribute__((ext_vector_type(8))) __bf16 bf16x8;
typedef __attribute__((ext_vector_type(4))) float floatx4;

static __device__ __forceinline__ float bf2f(unsigned short u) {
    union { unsigned int i; float f; } v; v.i = ((unsigned int)u) << 16; return v.f;
}
static __device__ __forceinline__ unsigned short f2bf(float f) {
    union { float f; unsigned int u; } v; v.f = f;
    unsigned int u = v.u;
    return (unsigned short)((u + 0x7FFFu + ((u >> 16) & 1u)) >> 16);   // RNE
}
static __device__ __forceinline__ float ld1(const void* p, int isbf, size_t i) {
    return isbf ? bf2f(((const unsigned short*)p)[i]) : ((const float*)p)[i];
}
static __device__ __forceinline__ float fast_tanh(float x) {
    float t = __expf(2.0f * x);
    return 1.0f - 2.0f * __builtin_amdgcn_rcpf(t + 1.0f);   // err ~2e-5
}
// one-wave bf16-vs-f32 detector: lanes 0..63 sample `words` u32 words; result in lane-reduced int
static __device__ __forceinline__ int detect_bf16_wave(const unsigned int* w, int words, int lane) {
    int pass = 0, tot = 0;
    for (int i = lane; i < words; i += 64) {
        unsigned int e = (w[i] >> 7) & 0xFF;
        tot++;
        if (e == 0 || (e >= 96 && e <= 140)) pass++;
    }
    for (int off = 32; off; off >>= 1) {
        pass += __shfl_xor(pass, off, 64);
        tot  += __shfl_xor(tot,  off, 64);
    }
    return (pass * 4 >= tot * 3) ? 1 : 0;
}

// ---------------- prep_all: detect(0-7) | lengths(8-39) | WeTf(40) | pb rows(41-240) ----
// WeTf layout: frag = nt*4+kks; WeTf[(frag*64+lane)*8+j] = We[kks*32+(lane>>4)*8+j][nt*16+(lane&15)]
__global__ __launch_bounds__(128) void prep_all_kernel(
    const void* __restrict__ Xs, const void* __restrict__ pos,
    const void* __restrict__ Xitem, const void* __restrict__ maskv,
    const void* __restrict__ origin, const void* __restrict__ Wp,
    const void* __restrict__ We, const void* __restrict__ zv,
    int* __restrict__ flags, unsigned short* __restrict__ WeTf,
    float* __restrict__ pb, int* __restrict__ lengths)
{
    int blk = blockIdx.x, t = threadIdx.x;
    int lane = t & 63;

    if (blk < 8) {                       // ---- global flags (used by scores/attnout) ----
        if (t >= 64) return;
        if (blk == 3) {
            const unsigned char* mb = (const unsigned char*)maskv;
            int f = 0;
            for (int i = t; i < 4096; i += 64)
                if ((i & 3) && mb[i]) f = 1;
            for (int off = 32; off; off >>= 1) f |= __shfl_xor(f, off, 64);
            if (t == 0) flags[3] = f;    // 1 => uint8 mask, 0 => int32 mask
            return;
        }
        const void* ptrs[8] = {Xs, pos, Xitem, maskv, origin, Wp, We, zv};
        const int counts[8] = {B_*S_*D_, S_*D_, B_*D_, 0, B_*N_*D_, D_*H_, D_*H_, H_};
        int words = counts[blk] / 2; if (words > 1024) words = 1024;
        int r = detect_bf16_wave((const unsigned int*)ptrs[blk], words, t);
        if (t == 0) flags[blk] = r;
        return;
    }

    if (blk < 40) {                      // ---- lengths: 32 b's per block ----
        __shared__ int fMk_s;
        const unsigned char* mb = (const unsigned char*)maskv;
        if (t < 64) {
            int f = 0;
            for (int i = t; i < 4096; i += 64)
                if ((i & 3) && mb[i]) f = 1;
            for (int off = 32; off; off >>= 1) f |= __shfl_xor(f, off, 64);
            if (t == 0) fMk_s = f;
        }
        __syncthreads();
        int fMk = fMk_s;
        int wv = t >> 6;
        int base = (blk - 8) * 32 + wv * 16;
        for (int bb = 0; bb < 16; ++bb) {
            int b = base + bb;
            int nz = 0;
            if (fMk) {
                const unsigned char* mp = mb + (size_t)b * S_;
                for (int i = lane; i < S_; i += 64) nz += (mp[i] != 0);
            } else {
                const int* mi = (const int*)maskv + (size_t)b * S_;
                for (int i = lane; i < S_; i += 64) nz += (mi[i] != 0);
            }
            for (int off = 32; off; off >>= 1) nz += __shfl_xor(nz, off, 64);
            if (lane == 0) lengths[b] = nz;
        }
        return;
    }

    if (blk == 40) {                     // ---- WeTf (fragment-swizzled transpose) ----
        __shared__ unsigned short T[128][136];
        __shared__ int fWe_s;
        if (t < 64) {
            int r = detect_bf16_wave((const unsigned int*)We, 1024, t);
            if (t == 0) fWe_s = r;
        }
        __syncthreads();
        int fWe = fWe_s;
        for (int c = t; c < 2048; c += 128) {
            int d = c >> 4, h8 = (c & 15) * 8;
            short8 v;
            if (fWe) {
                v = *(const short8*)((const unsigned short*)We + d * H_ + h8);
            } else {
                const float* p = (const float*)We + d * H_ + h8;
                float4 a = ((const float4*)p)[0], b = ((const float4*)p)[1];
                v[0] = (short)f2bf(a.x); v[1] = (short)f2bf(a.y);
                v[2] = (short)f2bf(a.z); v[3] = (short)f2bf(a.w);
                v[4] = (short)f2bf(b.x); v[5] = (short)f2bf(b.y);
                v[6] = (short)f2bf(b.z); v[7] = (short)f2bf(b.w);
            }
            *(short8*)(&T[d][h8]) = v;
        }
        __syncthreads();
        for (int i = t; i < 2048; i += 128) {
            int frag = i >> 6, ln = i & 63;
            int nt = frag >> 2, kks = frag & 3;
            int h = nt * 16 + (ln & 15);
            int dbase = kks * 32 + (ln >> 4) * 8;
            short8 v;
#pragma unroll
            for (int j = 0; j < 8; ++j) v[j] = (short)T[dbase + j][h];
            *(short8*)(WeTf + (size_t)i * 8) = v;
        }
        return;
    }

    // ---- pb row s = blk-41 ----
    {
        __shared__ float prow[D_];
        __shared__ int f2[2];
        if (t < 64) {
            int rp = detect_bf16_wave((const unsigned int*)pos, 1024, t);
            int rw = detect_bf16_wave((const unsigned int*)Wp, 1024, t);
            if (t == 0) { f2[0] = rp; f2[1] = rw; }
        }
        __syncthreads();
        int s = blk - 41, h = t;
        prow[h] = ld1(pos, f2[0], (size_t)s * D_ + h);
        __syncthreads();
        float acc = 0.f;
        if (f2[1]) {
            const unsigned short* W = (const unsigned short*)Wp;
            for (int d = 0; d < D_; ++d) acc = fmaf(prow[d], bf2f(W[d * H_ + h]), acc);
        } else {
            const float* W = (const float*)Wp;
            for (int d = 0; d < D_; ++d) acc = fmaf(prow[d], W[d * H_ + h], acc);
        }
        pb[s * H_ + h] = acc;
    }
}

// ---------------- K1: scores GEMM — dual-tile interleaved + uniform tile skip ----------------
// Block = 256 thr (4 waves), M = 128 rows/block (2 m-tiles/wave), grid = 1600.
__global__ __launch_bounds__(256) void scores_kernel(
    const void* __restrict__ Xs, const unsigned short* __restrict__ WeTf,
    const void* __restrict__ zv, const float* __restrict__ pb,
    const int* __restrict__ flags, const int* __restrict__ lengths,
    float* __restrict__ scores)
{
    __shared__ unsigned short Bsh[16384];   // 32 KB, frag-contiguous (same layout as WeTf)
    int t = threadIdx.x;
    int lane = t & 63, w = t >> 6;
    int quad = lane >> 4, mrow = lane & 15;
    int fXs = flags[0], fz = flags[7];
    int rb = blockIdx.x * 128;

    // block-level early-out: rows rb..rb+127 all invalid? (uniform scalar math)
    {
        int bidx = rb / S_, s0 = rb - bidx * S_;
        bool crosses = (s0 + 127 >= S_);            // contains next b's s=0 (len>=1 => valid)
        if (!crosses && s0 >= lengths[bidx]) return;
    }

    // one-time B stage: 8 coalesced 16B copies per thread
    for (int i = t; i < 2048; i += 256)
        *(short8*)(Bsh + i * 8) = *(const short8*)(WeTf + (size_t)i * 8);

    float zl[8];
#pragma unroll
    for (int nt = 0; nt < 8; ++nt) zl[nt] = ld1(zv, fz, nt * 16 + mrow);
    __syncthreads();

    int row0 = rb + w * 32;
    // wave-uniform validity of tiles [row0,row0+16) and [row0+16,row0+32)
    bool v[2];
#pragma unroll
    for (int mt = 0; mt < 2; ++mt) {
        int rf = row0 + mt * 16;
        int bidx = rf / S_, s0 = rf - bidx * S_;
        v[mt] = (s0 + 15 >= S_) || (s0 < lengths[bidx]);
    }
    if (!v[0] && !v[1]) return;   // no barriers after this point

    floatx4 accA[8], accB[8];
#pragma unroll
    for (int nt = 0; nt < 8; ++nt) {
        accA[nt][0] = 0.f; accA[nt][1] = 0.f; accA[nt][2] = 0.f; accA[nt][3] = 0.f;
        accB[nt][0] = 0.f; accB[nt][1] = 0.f; accB[nt][2] = 0.f; accB[nt][3] = 0.f;
    }

    auto loadA = [&](int r, int kks) -> bf16x8 {
        size_t roff = (size_t)r * D_ + kks * 32 + quad * 8;
        if (fXs) {
            short8 vv = *(const short8*)((const unsigned short*)Xs + roff);
            return __builtin_bit_cast(bf16x8, vv);
        }
        const float* p = (const float*)Xs + roff;
        float4 a = ((const float4*)p)[0], b = ((const float4*)p)[1];
        short8 vv;
        vv[0] = (short)f2bf(a.x); vv[1] = (short)f2bf(a.y);
        vv[2] = (short)f2bf(a.z); vv[3] = (short)f2bf(a.w);
        vv[4] = (short)f2bf(b.x); vv[5] = (short)f2bf(b.y);
        vv[6] = (short)f2bf(b.z); vv[7] = (short)f2bf(b.w);
        return __builtin_bit_cast(bf16x8, vv);
    };

    int mtv = v[0] ? 0 : 1;           // single-tile case
    if (v[0] && v[1]) {
        int r0 = row0 + mrow, r1 = row0 + 16 + mrow;
#pragma unroll
        for (int kks = 0; kks < 4; ++kks) {
            bf16x8 a0 = loadA(r0, kks), a1 = loadA(r1, kks);
#pragma unroll
            for (int nt = 0; nt < 8; ++nt) {
                short8 bv = *(const short8*)(Bsh + (((nt << 2) + kks) * 64 + lane) * 8);
                bf16x8 bf = __builtin_bit_cast(bf16x8, bv);
                accA[nt] = __builtin_amdgcn_mfma_f32_16x16x32_bf16(a0, bf, accA[nt], 0, 0, 0);
                accB[nt] = __builtin_amdgcn_mfma_f32_16x16x32_bf16(a1, bf, accB[nt], 0, 0, 0);
            }
        }
    } else {
        int r0 = row0 + mtv * 16 + mrow;
#pragma unroll
        for (int kks = 0; kks < 4; ++kks) {
            bf16x8 a0 = loadA(r0, kks);
#pragma unroll
            for (int nt = 0; nt < 8; ++nt) {
                short8 bv = *(const short8*)(Bsh + (((nt << 2) + kks) * 64 + lane) * 8);
                bf16x8 bf = __builtin_bit_cast(bf16x8, bv);
                accA[nt] = __builtin_amdgcn_mfma_f32_16x16x32_bf16(a0, bf, accA[nt], 0, 0, 0);
            }
        }
    }

    auto epilogue = [&](const floatx4* acc8, int rowbase) {
        // C layout: col=mrow, row=quad*4+reg
#pragma unroll
        for (int reg = 0; reg < 4; ++reg) {
            int grow = rowbase + quad * 4 + reg;
            int s = grow % S_;
            const float* pbrow = pb + (size_t)s * H_;
            float rs = 0.f;
#pragma unroll
            for (int nt = 0; nt < 8; ++nt)
                rs = fmaf(fast_tanh(acc8[nt][reg] + pbrow[nt * 16 + mrow]), zl[nt], rs);
#pragma unroll
            for (int off = 1; off < 16; off <<= 1)
                rs += __shfl_xor(rs, off, 64);
            if (mrow == 0) scores[grow] = rs;
        }
    };
    if (v[0] && v[1]) {
        epilogue(accA, row0);
        epilogue(accB, row0 + 16);
    } else {
        epilogue(accA, row0 + mtv * 16);
    }
}

// ---------------- K2: per-b softmax, weighted sum, inner, pos/neg losses ----------------
__global__ __launch_bounds__(256) void attnout_kernel(
    const void* __restrict__ Xs, const void* __restrict__ Xitem,
    const void* __restrict__ origin, const float* __restrict__ scores,
    const int* __restrict__ flags, const int* __restrict__ lengths,
    float* __restrict__ pos_loss, float* __restrict__ neg_sum,
    float* __restrict__ out)
{
    int b = blockIdx.x, t = threadIdx.x;
    int wv = t >> 6, lane = t & 63;
    int fXs = flags[0], fXi = flags[2], fOr = flags[4];
    __shared__ float attn[256];
    __shared__ float att_out[D_];
    __shared__ float lastv[D_];
    __shared__ float outv[D_];
    __shared__ float partial[8][D_];
    __shared__ float p_oo[4][64];
    __shared__ float p_ov[4][64];
    __shared__ float red[16];
    __shared__ float sc1s, sc2s, vvs;

    // --- preload this thread's origin slice into registers (latency hidden) ---
    int nn = t >> 2, part = t & 3;       // thread -> (n, quarter-of-D)
    float o_f[32];
    if (fOr) {
        const unsigned short* p = (const unsigned short*)origin + ((size_t)b * N_ + nn) * D_ + part * 32;
#pragma unroll
        for (int j = 0; j < 4; ++j) {
            uint4 u = *(const uint4*)(p + j * 8);
            o_f[j*8+0] = bf2f((unsigned short)(u.x & 0xffff));
            o_f[j*8+1] = bf2f((unsigned short)(u.x >> 16));
            o_f[j*8+2] = bf2f((unsigned short)(u.y & 0xffff));
            o_f[j*8+3] = bf2f((unsigned short)(u.y >> 16));
            o_f[j*8+4] = bf2f((unsigned short)(u.z & 0xffff));
            o_f[j*8+5] = bf2f((unsigned short)(u.z >> 16));
            o_f[j*8+6] = bf2f((unsigned short)(u.w & 0xffff));
            o_f[j*8+7] = bf2f((unsigned short)(u.w >> 16));
        }
    } else {
        const float* p = (const float*)origin + ((size_t)b * N_ + nn) * D_ + part * 32;
#pragma unroll
        for (int j = 0; j < 8; ++j) {
            float4 v = *(const float4*)(p + j * 4);
            o_f[j*4+0] = v.x; o_f[j*4+1] = v.y; o_f[j*4+2] = v.z; o_f[j*4+3] = v.w;
        }
    }

    int length = lengths[b];      // >= 1
    int last = length - 1;

    // --- softmax over valid prefix ---
    float sc = (t < length) ? scores[(size_t)b * S_ + t] : -INFINITY;
    float m = sc;
    for (int off = 32; off; off >>= 1) m = fmaxf(m, __shfl_xor(m, off, 64));
    if (lane == 0) red[wv] = m;
    __syncthreads();
    if (t == 0) sc1s = fmaxf(fmaxf(red[0], red[1]), fmaxf(red[2], red[3]));
    __syncthreads();
    float e = (t < length) ? expf(sc - sc1s) : 0.f;
    float r = e;
    for (int off = 32; off; off >>= 1) r += __shfl_xor(r, off, 64);
    __syncthreads();
    if (lane == 0) red[wv] = r;
    __syncthreads();
    if (t == 0) sc2s = red[0] + red[1] + red[2] + red[3];
    __syncthreads();
    attn[t] = e / sc2s;       // 0 beyond length (incl. 200..255)
    __syncthreads();

    // --- attention_output[d] = sum_{s<length} attn[s] * X[b,s,d] (uniform bound) ---
    {
        int sp = t >> 5;               // s offset 0..7
        int d4 = (t & 31) * 4;         // 4 contiguous d
        float a0 = 0, a1 = 0, a2 = 0, a3 = 0;
        if (fXs) {
#pragma unroll 5
            for (int s = sp; s < length; s += 8) {
                float ww = attn[s];
                uint2 u = *(const uint2*)((const unsigned short*)Xs + ((size_t)b * S_ + s) * D_ + d4);
                a0 = fmaf(ww, bf2f((unsigned short)(u.x & 0xffff)), a0);
                a1 = fmaf(ww, bf2f((unsigned short)(u.x >> 16)), a1);
                a2 = fmaf(ww, bf2f((unsigned short)(u.y & 0xffff)), a2);
                a3 = fmaf(ww, bf2f((unsigned short)(u.y >> 16)), a3);
            }
        } else {
#pragma unroll 5
            for (int s = sp; s < length; s += 8) {
                float ww = attn[s];
                float4 u = *(const float4*)((const float*)Xs + ((size_t)b * S_ + s) * D_ + d4);
                a0 = fmaf(ww, u.x, a0);
                a1 = fmaf(ww, u.y, a1);
                a2 = fmaf(ww, u.z, a2);
                a3 = fmaf(ww, u.w, a3);
            }
        }
        partial[sp][d4] = a0; partial[sp][d4 + 1] = a1;
        partial[sp][d4 + 2] = a2; partial[sp][d4 + 3] = a3;
    }
    __syncthreads();
    if (t < D_) {
        float v = 0.f;
#pragma unroll
        for (int p = 0; p < 8; ++p) v += partial[p][t];
        att_out[t] = v;
        float lv = attn[last] * ld1(Xs, fXs, ((size_t)b * S_ + last) * D_ + t);
        lastv[t] = lv;
        outv[t] = v - lv;       // out_vec = attention_output - last_vec
    }
    __syncthreads();

    // --- inner = dot(att_out, X_item[b]); write concated row (f32) ---
    {
        float pi = (t < D_) ? att_out[t] * ld1(Xitem, fXi, (size_t)b * D_ + t) : 0.f;
        for (int off = 32; off; off >>= 1) pi += __shfl_xor(pi, off, 64);
        if (lane == 0) red[wv] = pi;
        __syncthreads();
        if (t < D_) out[(size_t)b * (D_ + 1) + t] = att_out[t];
        if (t == 0)
            out[(size_t)b * (D_ + 1) + D_] = red[0] + red[1] + red[2] + red[3];
        __syncthreads();
    }

    // --- pos loss: cos(last_vec, out_vec) ---
    {
        float l_ = (t < D_) ? lastv[t] : 0.f;
        float o_ = (t < D_) ? outv[t] : 0.f;
        float r0 = l_ * l_, r1 = l_ * o_, r2 = o_ * o_;
        for (int off = 32; off; off >>= 1) {
            r0 += __shfl_xor(r0, off, 64);
            r1 += __shfl_xor(r1, off, 64);
            r2 += __shfl_xor(r2, off, 64);
        }
        if (lane == 0) { red[wv] = r0; red[4 + wv] = r1; red[8 + wv] = r2; }
        __syncthreads();
        if (t == 0) {
            float ll = red[0] + red[1] + red[2] + red[3];
            float lo = red[4] + red[5] + red[6] + red[7];
            float oo = red[8] + red[9] + red[10] + red[11];
            float cosv = lo / (sqrtf(fmaxf(ll, 1e-12f)) * sqrtf(fmaxf(oo, 1e-12f)));
            float pl = 0.5f * (1.f - cosv);
            pos_loss[b] = log1pf(expf(-pl));
            vvs = oo;
        }
        __syncthreads();
    }

    // --- neg losses: thread (nn,part) computes quarter-dot; LDS reduce ---
    {
        float o_oo = 0.f, o_ov = 0.f;
#pragma unroll
        for (int jj = 0; jj < 32; ++jj) {
            int j = (jj + part * 8) & 31;           // bank-rotated outv read
            float wv_ = outv[part * 32 + j];
            o_oo = fmaf(o_f[j], o_f[j], o_oo);
            o_ov = fmaf(o_f[j], wv_, o_ov);
        }
        p_oo[part][nn] = o_oo;
        p_ov[part][nn] = o_ov;
        __syncthreads();
        if (t < 64) {
            float oo = p_oo[0][t] + p_oo[1][t] + p_oo[2][t] + p_oo[3][t];
            float ov = p_ov[0][t] + p_ov[1][t] + p_ov[2][t] + p_ov[3][t];
            float cosn = ov / (sqrtf(fmaxf(oo, 1e-12f)) * sqrtf(fmaxf(vvs, 1e-12f)));
            float nl = 0.5f * (1.f - cosn);
            float nloss = log1pf(expf(nl));
            for (int off = 32; off; off >>= 1) nloss += __shfl_xor(nloss, off, 64);
            if (t == 0) neg_sum[b] = nloss;
        }
    }
}

// ---------------- K3: aux[b] = sum_b'(pos_loss) + neg_sum[b] (f32) ----------------
__global__ __launch_bounds__(1024) void final_kernel(
    const float* __restrict__ pos_loss,
    const float* __restrict__ neg_sum,
    float* __restrict__ out)
{
    __shared__ float red[16];
    int t = threadIdx.x;
    float v = pos_loss[t];
    for (int off = 32; off; off >>= 1) v += __shfl_xor(v, off, 64);
    if ((t & 63) == 0) red[t >> 6] = v;
    __syncthreads();
    if (t == 0) {
        float s = 0.f;
#pragma unroll
        for (int i = 0; i < 16; ++i) s += red[i];
        red[0] = s;
    }
    __syncthreads();
    out[(size_t)B_ * (D_ + 1) + t] = red[0] + neg_sum[t];
}

extern "C" void kernel_launch(void* const* d_in, const int* in_sizes, int n_in,
                              void* d_out, int out_size, void* d_ws, size_t ws_size,
                              hipStream_t stream) {
    const void* Xs     = d_in[0]; // X_series [B,S,D]
    const void* pos    = d_in[1]; // pos_series [S,D]
    const void* Xitem  = d_in[2]; // X_item [B,D]
    const void* mask   = d_in[3]; // valid_mask [B,S]
    const void* origin = d_in[4]; // origin [B,N,D]
    const void* Wp     = d_in[5]; // [D,H]
    const void* We     = d_in[6]; // [D,H]
    const void* zv     = d_in[7]; // [H]

    int*   flags    = (int*)d_ws;                                  // 128 B
    unsigned short* WeTf = (unsigned short*)((char*)d_ws + 128);   // 32 KB swizzled
    float* pb       = (float*)((char*)d_ws + 128 + 32768);         // 25600 f32
    float* scores   = pb + 25600;                                  // 204800 f32
    float* pos_loss = scores + 204800;                             // 1024 f32
    float* neg_sum  = pos_loss + B_;                               // 1024 f32
    int*   lengths  = (int*)(neg_sum + B_);                        // 1024 i32
    float* out = (float*)d_out;                                    // f32 output

    prep_all_kernel<<<241, 128, 0, stream>>>(Xs, pos, Xitem, mask, origin, Wp, We, zv,
                                             flags, WeTf, pb, lengths);
    scores_kernel<<<(B_ * S_) / 128, 256, 0, stream>>>(Xs, WeTf, zv, pb, flags, lengths, scores);
    attnout_kernel<<<B_, 256, 0, stream>>>(Xs, Xitem, origin, scores, flags, lengths,
                                           pos_loss, neg_sum, out);
    final_kernel<<<1, 1024, 0, stream>>>(pos_loss, neg_sum, out);
}